// Round 2
// baseline (313.933 us; speedup 1.0000x reference)
//
#include <hip/hip_runtime.h>
#include <cstdint>

// CamPoseNet: bit-faithful JAX threefry replication (validated round 1),
// restructured for speed:
//  - subkey chain (wave-uniform split() sequence) precomputed once by a tiny
//    pre-kernel into d_ws, staged to LDS in the main kernel
//  - per-lane state machine: each lane walks (row, attempt-t) independently,
//    one rejection draw per wave iteration; on accept it stores and advances
//    to its next strided row. Removes per-row wave-max divergence cost.
// All float ops on the accept-decision path use __f*_rn intrinsics (no FMA
// contraction) — matches XLA:CPU strict mul/add. Do not alter any arithmetic.

#define DEVI __device__ __forceinline__
#define MAXT 96
#define KROWS 8

DEVI uint32_t rotl32(uint32_t v, int s) { return (v << s) | (v >> (32 - s)); }

// Threefry-2x32, 20 rounds (jax._src.prng.threefry2x32).
DEVI void tf2x32(uint32_t k0, uint32_t k1, uint32_t x0, uint32_t x1,
                 uint32_t& o0, uint32_t& o1) {
  const uint32_t kx = k0 ^ k1 ^ 0x1BD11BDAu;
  x0 += k0; x1 += k1;
#define TFR(r) x0 += x1; x1 = rotl32(x1, (r)); x1 ^= x0;
  TFR(13) TFR(15) TFR(26) TFR(6)
  x0 += k1; x1 += kx + 1u;
  TFR(17) TFR(29) TFR(16) TFR(24)
  x0 += kx; x1 += k0 + 2u;
  TFR(13) TFR(15) TFR(26) TFR(6)
  x0 += k0; x1 += k1 + 3u;
  TFR(17) TFR(29) TFR(16) TFR(24)
  x0 += k1; x1 += kx + 4u;
  TFR(13) TFR(15) TFR(26) TFR(6)
  x0 += kx; x1 += k0 + 5u;
#undef TFR
  o0 = x0; o1 = x1;
}

// XLA:CPU Cephes-style f32 log, strict mul/add. x > 0, normal.
DEVI float xla_logf_pos(float xf) {
  uint32_t bits = __float_as_uint(xf);
  float e = (float)((int)(bits >> 23) - 126);
  float m = __uint_as_float((bits & 0x007fffffu) | 0x3f000000u);  // [0.5,1)
  if (m < 0.70710678118654752440f) {
    e = __fsub_rn(e, 1.0f);
    m = __fadd_rn(__fsub_rn(m, 1.0f), m);
  } else {
    m = __fsub_rn(m, 1.0f);
  }
  float z = __fmul_rn(m, m);
  float y = 7.0376836292e-2f;
  y = __fadd_rn(__fmul_rn(y, m), -1.1514610310e-1f);
  y = __fadd_rn(__fmul_rn(y, m),  1.1676998740e-1f);
  y = __fadd_rn(__fmul_rn(y, m), -1.2420140846e-1f);
  y = __fadd_rn(__fmul_rn(y, m),  1.4249322787e-1f);
  y = __fadd_rn(__fmul_rn(y, m), -1.6668057665e-1f);
  y = __fadd_rn(__fmul_rn(y, m),  2.0000714765e-1f);
  y = __fadd_rn(__fmul_rn(y, m), -2.4999993993e-1f);
  y = __fadd_rn(__fmul_rn(y, m),  3.3333331174e-1f);
  y = __fmul_rn(y, m);
  y = __fmul_rn(y, z);
  y = __fadd_rn(y, __fmul_rn(e, -2.12194440e-4f));
  y = __fsub_rn(y, __fmul_rn(z, 0.5f));
  float r = __fadd_rn(m, y);
  r = __fadd_rn(r, __fmul_rn(e, 0.693359375f));
  return r;
}

DEVI float xla_log1pf(float v) {
  if (fabsf(v) < 1e-4f) {
    return __fmul_rn(__fadd_rn(__fmul_rn(-0.5f, v), 1.0f), v);
  }
  return xla_logf_pos(__fadd_rn(v, 1.0f));
}

DEVI float xla_erfinvf(float x) {
  float w = -xla_log1pf(-__fmul_rn(x, x));
  float p;
  if (w < 5.0f) {
    float q = __fsub_rn(w, 2.5f);
    p = 2.81022636e-08f;
    p = __fadd_rn(__fmul_rn(p, q),  3.43273939e-07f);
    p = __fadd_rn(__fmul_rn(p, q), -3.5233877e-06f);
    p = __fadd_rn(__fmul_rn(p, q), -4.39150654e-06f);
    p = __fadd_rn(__fmul_rn(p, q),  0.00021858087f);
    p = __fadd_rn(__fmul_rn(p, q), -0.00125372503f);
    p = __fadd_rn(__fmul_rn(p, q), -0.00417768164f);
    p = __fadd_rn(__fmul_rn(p, q),  0.246640727f);
    p = __fadd_rn(__fmul_rn(p, q),  1.50140941f);
  } else {
    float q = __fsub_rn(sqrtf(w), 3.0f);
    p = -0.000200214257f;
    p = __fadd_rn(__fmul_rn(p, q),  0.000100950558f);
    p = __fadd_rn(__fmul_rn(p, q),  0.00134934322f);
    p = __fadd_rn(__fmul_rn(p, q), -0.00367342844f);
    p = __fadd_rn(__fmul_rn(p, q),  0.00573950773f);
    p = __fadd_rn(__fmul_rn(p, q), -0.0076224613f);
    p = __fadd_rn(__fmul_rn(p, q),  0.00943887047f);
    p = __fadd_rn(__fmul_rn(p, q),  1.00167406f);
    p = __fadd_rn(__fmul_rn(p, q),  2.83297682f);
  }
  return __fmul_rn(p, x);
}

DEVI float u01_from_bits(uint32_t bits) {
  return __fsub_rn(__uint_as_float(0x3f800000u | (bits >> 9)), 1.0f);
}

// ---------------------------------------------------------------------------
// Pre-kernel: compute the split() subkey chain once.
// chain[t] = {s1a, s1b, s2a, s2b} at while-iteration t.
// 3-lane parallel: lane j computes tf(key, 0, {1,2,0}[j]); lane2's output is
// the carry key, broadcast via __shfl.
__global__ void chain_kernel(const int* __restrict__ seedp,
                             uint4* __restrict__ chain) {
  int lane = threadIdx.x;
  if (lane >= 3) return;
  uint32_t ka = 0u, kb = (uint32_t)seedp[0];
  uint32_t x1i = (lane == 2) ? 0u : (uint32_t)(lane + 1);
  for (int t = 0; t < MAXT; ++t) {
    uint32_t o0, o1;
    tf2x32(ka, kb, 0u, x1i, o0, o1);
    uint32_t p0 = __shfl(o0, 1, 64);
    uint32_t p1 = __shfl(o1, 1, 64);
    if (lane == 0) chain[t] = make_uint4(o0, o1, p0, p1);
    ka = __shfl(o0, 2, 64);
    kb = __shfl(o1, 2, 64);
  }
}

// ---------------------------------------------------------------------------
__global__ __launch_bounds__(256) void campose_kernel(
    const float* __restrict__ q, const float* __restrict__ Z,
    float* __restrict__ out, const uint4* __restrict__ chain_g,
    int N, int T) {
  __shared__ uint4 chain[MAXT];
  for (int i = threadIdx.x; i < MAXT; i += 256) chain[i] = chain_g[i];
  __syncthreads();

  const float lam0 = 1e-6f;
  const float sgi0 = __fadd_rn(1.0f, __fmul_rn(2.0f, 1e-6f));
  const float sig0 = sqrtf(__fdiv_rn(1.0f, sgi0));

  int r = blockIdx.x * 256 + threadIdx.x;
  int t = 0;
  bool have = (r < N);

  float lam1 = 0, lam2 = 0, lam3 = 0;
  float sgi1 = 1, sgi2 = 1, sgi3 = 1;
  float sig1 = 1, sig2 = 1, sig3 = 1;
  if (have) {
    lam1 = -Z[r * 3 + 0]; lam2 = -Z[r * 3 + 1]; lam3 = -Z[r * 3 + 2];
    sgi1 = __fadd_rn(1.0f, __fmul_rn(2.0f, lam1));
    sgi2 = __fadd_rn(1.0f, __fmul_rn(2.0f, lam2));
    sgi3 = __fadd_rn(1.0f, __fmul_rn(2.0f, lam3));
    sig1 = sqrtf(__fdiv_rn(1.0f, sgi1));
    sig2 = sqrtf(__fdiv_rn(1.0f, sgi2));
    sig3 = sqrtf(__fdiv_rn(1.0f, sgi3));
  }

  while (__ballot(have)) {
    if (have) {
      uint4 ck = chain[t];
      const uint32_t base = ((uint32_t)r) * 4u;

      // 4 normal draws (key = s1, counters base..base+3)
      float y[4];
      float sigv[4] = {sig0, sig1, sig2, sig3};
#pragma unroll
      for (int j = 0; j < 4; ++j) {
        uint32_t o0, o1;
        tf2x32(ck.x, ck.y, 0u, base + (uint32_t)j, o0, o1);
        float u = u01_from_bits(o0 ^ o1);
        float xin = __fadd_rn(__fmul_rn(u, 2.0f), -0.99999994f);
        xin = fmaxf(-0.99999994f, xin);
        float nv = __fmul_rn(1.41421356237309504880f, xla_erfinvf(xin));
        y[j] = __fmul_rn(nv, sigv[j]);
      }

      // normalize (sequential reduce order)
      float n2 = __fmul_rn(y[0], y[0]);
      n2 = __fadd_rn(n2, __fmul_rn(y[1], y[1]));
      n2 = __fadd_rn(n2, __fmul_rn(y[2], y[2]));
      n2 = __fadd_rn(n2, __fmul_rn(y[3], y[3]));
      float nr = sqrtf(n2);
#pragma unroll
      for (int j = 0; j < 4; ++j) y[j] = __fdiv_rn(y[j], nr);

      float y2[4];
#pragma unroll
      for (int j = 0; j < 4; ++j) y2[j] = __fmul_rn(y[j], y[j]);

      float s1 = __fmul_rn(y2[0], lam0);
      s1 = __fadd_rn(s1, __fmul_rn(y2[1], lam1));
      s1 = __fadd_rn(s1, __fmul_rn(y2[2], lam2));
      s1 = __fadd_rn(s1, __fmul_rn(y2[3], lam3));

      float s2 = __fmul_rn(y2[0], sgi0);
      s2 = __fadd_rn(s2, __fmul_rn(y2[1], sgi1));
      s2 = __fadd_rn(s2, __fmul_rn(y2[2], sgi2));
      s2 = __fadd_rn(s2, __fmul_rn(y2[3], sgi3));

      float lr = __fsub_rn(-s1, 2.7725887298583984f);  // 2*f32(ln 4)
      lr = __fadd_rn(lr, 1.5f);
      lr = __fadd_rn(lr, __fmul_rn(2.0f, xla_logf_pos(s2)));

      // uniform draw (key = s2-subkey, counter r)
      uint32_t o0, o1;
      tf2x32(ck.z, ck.w, 0u, (uint32_t)r, o0, o1);
      float uu = u01_from_bits(o0 ^ o1);
      float lu = (uu > 0.0f) ? xla_logf_pos(uu) : -__builtin_inff();

      ++t;
      if ((lu < lr) || (t >= MAXT)) {
        // epilogue: qn = q/||q||, out = E^T y
        float a = q[r * 4 + 0], b = q[r * 4 + 1];
        float c = q[r * 4 + 2], d = q[r * 4 + 3];
        float qn2 = __fmul_rn(a, a);
        qn2 = __fadd_rn(qn2, __fmul_rn(b, b));
        qn2 = __fadd_rn(qn2, __fmul_rn(c, c));
        qn2 = __fadd_rn(qn2, __fmul_rn(d, d));
        float qnr = sqrtf(qn2);
        a = __fdiv_rn(a, qnr); b = __fdiv_rn(b, qnr);
        c = __fdiv_rn(c, qnr); d = __fdiv_rn(d, qnr);

        float o0v = __fadd_rn(__fadd_rn(__fadd_rn(__fmul_rn(a, y[0]), __fmul_rn(b, y[1])),
                                        __fmul_rn(c, y[2])), __fmul_rn(d, y[3]));
        float o1v = __fadd_rn(__fadd_rn(__fadd_rn(__fmul_rn(-b, y[0]), __fmul_rn(a, y[1])),
                                        __fmul_rn(-d, y[2])), __fmul_rn(c, y[3]));
        float o2v = __fadd_rn(__fadd_rn(__fadd_rn(__fmul_rn(-c, y[0]), __fmul_rn(d, y[1])),
                                        __fmul_rn(a, y[2])), __fmul_rn(-b, y[3]));
        float o3v = __fadd_rn(__fadd_rn(__fadd_rn(__fmul_rn(d, y[0]), __fmul_rn(c, y[1])),
                                        __fmul_rn(-b, y[2])), __fmul_rn(-a, y[3]));
        *reinterpret_cast<float4*>(out + (size_t)r * 4) =
            make_float4(o0v, o1v, o2v, o3v);

        // advance to next strided row
        r += T;
        t = 0;
        have = (r < N);
        if (have) {
          lam1 = -Z[r * 3 + 0]; lam2 = -Z[r * 3 + 1]; lam3 = -Z[r * 3 + 2];
          sgi1 = __fadd_rn(1.0f, __fmul_rn(2.0f, lam1));
          sgi2 = __fadd_rn(1.0f, __fmul_rn(2.0f, lam2));
          sgi3 = __fadd_rn(1.0f, __fmul_rn(2.0f, lam3));
          sig1 = sqrtf(__fdiv_rn(1.0f, sgi1));
          sig2 = sqrtf(__fdiv_rn(1.0f, sgi2));
          sig3 = sqrtf(__fdiv_rn(1.0f, sgi3));
        }
      }
    }
  }
}

extern "C" void kernel_launch(void* const* d_in, const int* in_sizes, int n_in,
                              void* d_out, int out_size, void* d_ws, size_t ws_size,
                              hipStream_t stream) {
  const float* q = (const float*)d_in[0];
  const float* Z = (const float*)d_in[1];
  const int* seed = (const int*)d_in[2];
  float* out = (float*)d_out;
  int N = in_sizes[0] / 4;

  uint4* chain = (uint4*)d_ws;
  chain_kernel<<<1, 64, 0, stream>>>(seed, chain);

  // KROWS rows per lane, strided by total thread count T
  int T = ((N + KROWS - 1) / KROWS + 255) & ~255;
  int grid = T / 256;
  campose_kernel<<<grid, 256, 0, stream>>>(q, Z, out, chain, N, T);
}